// Round 3
// baseline (40.912 us; speedup 1.0000x reference)
//
#include <hip/hip_runtime.h>

// GCNConv, full upper-tri graph + self loops, B=512, N=64, C=O=256.
// out[b,i,:] = relu( (1/sqrt(i+1)) * sum_{j<=i} (X[b]W)[j,:]/sqrt(j+1) + bias )
//
// R3: barrier-free streaming. 2048 one-wave blocks, each owns (graph, 64-col
// panel). No LDS, no __syncthreads. A-frags gathered straight from global f32
// X and converted to bf16 in regs; B-frags from pre-transposed bf16 Wt (wprep).
// Same-graph panels mapped to the same XCD for L2 reuse of X.

#define BATCH 512
#define NNODE 64
#define CIN   256
#define COUT  256

typedef __bf16 bf16x8 __attribute__((ext_vector_type(8)));
typedef float  f32x4  __attribute__((ext_vector_type(4)));

__device__ __forceinline__ unsigned int f2bf_bits(float f) {
    unsigned int u = __builtin_bit_cast(unsigned int, f);
    return (u + 0x7fffu + ((u >> 16) & 1u)) >> 16;
}

__global__ __launch_bounds__(64, 2) void gcn_fused(
    const float* __restrict__ X,
    const unsigned short* __restrict__ WT,   // bf16 bits, [COUT][CIN]
    const float* __restrict__ bias,
    float* __restrict__ out)
{
    const int lane = threadIdx.x;            // 0..63
    const int g    = lane >> 4;              // k-group (A/B), row-group (C/D)
    const int c    = lane & 15;

    // bid -> (graph b, panel p) with all 4 panels of b on the same XCD
    // (XCD = bid & 7 under round-robin dispatch; perf heuristic only).
    const int bid = blockIdx.x;
    const int xcd = bid & 7;
    const int k5  = bid >> 3;                // 0..255
    const int b   = (k5 >> 2) * 8 + xcd;     // graph 0..511
    const int p   = k5 & 3;                  // column panel 0..3

    const float* xb = X + (size_t)b * (NNODE * CIN);
    const unsigned short* WTb = WT + (size_t)(p * 64 + c) * CIN + g * 8;

    f32x4 acc[4][4] = {};                    // [mt][nt]; row=mt*16+g*4+r, col=nt*16+c

#pragma unroll
    for (int kk = 0; kk < 8; ++kk) {         // K = 256 = 8 x 32
        bf16x8 a[4];
#pragma unroll
        for (int mt = 0; mt < 4; ++mt) {
            // A[row=mt*16+c][k=kk*32+g*8 .. +7] from global f32, cvt to bf16
            const float* pa = xb + (mt * 16 + c) * CIN + kk * 32 + g * 8;
            float4 v0 = *reinterpret_cast<const float4*>(pa);
            float4 v1 = *reinterpret_cast<const float4*>(pa + 4);
            bf16x8 t;
            t[0] = (__bf16)v0.x; t[1] = (__bf16)v0.y;
            t[2] = (__bf16)v0.z; t[3] = (__bf16)v0.w;
            t[4] = (__bf16)v1.x; t[5] = (__bf16)v1.y;
            t[6] = (__bf16)v1.z; t[7] = (__bf16)v1.w;
            a[mt] = t;
        }
        bf16x8 bf[4];
#pragma unroll
        for (int nt = 0; nt < 4; ++nt)
            // B[k=kk*32+g*8..+7][col=p*64+nt*16+c] == Wt[col][k..k+7] contiguous
            bf[nt] = *reinterpret_cast<const bf16x8*>(WTb + nt * 16 * CIN + kk * 32);
#pragma unroll
        for (int mt = 0; mt < 4; ++mt)
#pragma unroll
            for (int nt = 0; nt < 4; ++nt)
                acc[mt][nt] = __builtin_amdgcn_mfma_f32_16x16x32_bf16(
                    a[mt], bf[nt], acc[mt][nt], 0, 0, 0);
    }

    // ---- epilogue: scale rows by 1/sqrt(j+1), prefix-sum over 64 rows ----
    float t[4][4];                           // chunk totals [mt][nt]
#pragma unroll
    for (int mt = 0; mt < 4; ++mt) {
        const int rbase = mt * 16 + g * 4;
        float d0 = rsqrtf((float)(rbase + 1));
        float d1 = rsqrtf((float)(rbase + 2));
        float d2 = rsqrtf((float)(rbase + 3));
        float d3 = rsqrtf((float)(rbase + 4));
#pragma unroll
        for (int nt = 0; nt < 4; ++nt) {
            f32x4 v = acc[mt][nt];
            v[0] *= d0; v[1] *= d1; v[2] *= d2; v[3] *= d3;
            v[1] += v[0]; v[2] += v[1]; v[3] += v[2];
            acc[mt][nt] = v;
            t[mt][nt] = v[3];
        }
    }
    // cross-chunk exclusive scan over 16 chunks (q = mt*4 + g) via shfl
    float O[4][4];                           // [nt][mt]
#pragma unroll
    for (int nt = 0; nt < 4; ++nt) {
        float S = 0.0f;
#pragma unroll
        for (int q = 0; q < 16; ++q) {
            const int mtq = q >> 2, gq = q & 3;
            float v = __shfl(t[mtq][nt], c + (gq << 4), 64);
            if (gq == g) O[nt][mtq] = S;
            S += v;
        }
    }

    float bias_c[4];
#pragma unroll
    for (int nt = 0; nt < 4; ++nt)
        bias_c[nt] = bias[p * 64 + nt * 16 + c];

    float* ob = out + (size_t)b * (NNODE * COUT) + (p * 64 + c);
#pragma unroll
    for (int mt = 0; mt < 4; ++mt) {
#pragma unroll
        for (int r = 0; r < 4; ++r) {
            const int row = mt * 16 + g * 4 + r;
            float dr = rsqrtf((float)(row + 1));
#pragma unroll
            for (int nt = 0; nt < 4; ++nt) {
                float val = (acc[mt][nt][r] + O[nt][mt]) * dr + bias_c[nt];
                ob[row * COUT + nt * 16] = fmaxf(val, 0.0f);
            }
        }
    }
}

// W (f32, [K=256][N=256]) -> Wt (bf16 bits, [N=256][K=256])
__global__ void wprep(const float* __restrict__ W, unsigned short* __restrict__ Wt) {
    __shared__ unsigned short tile[64][72];
    const int tid = threadIdx.x;
    const int tk  = blockIdx.x & 3;
    const int tn  = blockIdx.x >> 2;
#pragma unroll
    for (int i = 0; i < 16; ++i) {
        int idx = tid + i * 256;
        int r  = idx >> 6;
        int cc = idx & 63;
        tile[cc][r] = (unsigned short)f2bf_bits(W[(tk * 64 + r) * 256 + tn * 64 + cc]);
    }
    __syncthreads();
#pragma unroll
    for (int i = 0; i < 16; ++i) {
        int idx = tid + i * 256;
        int rr = idx >> 6;
        int cc = idx & 63;
        Wt[(tn * 64 + rr) * 256 + tk * 64 + cc] = tile[rr][cc];
    }
}

extern "C" void kernel_launch(void* const* d_in, const int* in_sizes, int n_in,
                              void* d_out, int out_size, void* d_ws, size_t ws_size,
                              hipStream_t stream) {
    const float* x = (const float*)d_in[0];
    const float* W = (const float*)d_in[1];
    const float* bsp = (const float*)d_in[2];
    float* out = (float*)d_out;
    unsigned short* Wt = (unsigned short*)d_ws;

    hipLaunchKernelGGL(wprep, dim3(16), dim3(256), 0, stream, W, Wt);
    hipLaunchKernelGGL(gcn_fused, dim3(BATCH * 4), dim3(64), 0, stream, x, Wt, bsp, out);
}

// Round 4
// 27.527 us; speedup vs baseline: 1.4863x; 1.4863x over previous
//
#include <hip/hip_runtime.h>

// GCNConv, full upper-tri graph + self loops, B=512, N=64, C=O=256.
// out[b,i,:] = relu( (1/sqrt(i+1)) * sum_{j<=i} (X[b]W)[j,:]/sqrt(j+1) + bias )
//
// R5: traffic-minimal + overlap. Grid 256 x 512thr (1 block/CU, 2 waves/SIMD).
// Each block: 2 graphs, W-frags in regs (read once/block -> 32MB total),
// both X staged to LDS (nt-loads), kk-loop interleaves both graphs' MFMAs,
// xor-butterfly scan, nt-stores. Slow-pool traffic ~64-96MB @ ~4.8TB/s.

#define BATCH 512
#define NNODE 64
#define CIN   256
#define COUT  256

typedef __bf16 bf16x8 __attribute__((ext_vector_type(8)));
typedef float  f32x4  __attribute__((ext_vector_type(4)));

__device__ __forceinline__ unsigned int f2bf_bits(float f) {
    unsigned int u = __builtin_bit_cast(unsigned int, f);
    return (u + 0x7fffu + ((u >> 16) & 1u)) >> 16;
}

__global__ __launch_bounds__(512, 2) void gcn_fused(
    const float* __restrict__ X,
    const unsigned short* __restrict__ WT,   // bf16 bits, [COUT][CIN]
    const float* __restrict__ bias,
    float* __restrict__ out)
{
    __shared__ uint4 Xs4[2][2048];           // [graph][32KB] swizzled bf16 X
    const int tid  = threadIdx.x;
    const int lane = tid & 63;
    const int w    = tid >> 6;               // wave 0..7: cols [w*32, w*32+32)
    const int g    = lane >> 4;
    const int c    = lane & 15;
    const int colbase = w * 32;
    const int xg   = blockIdx.x * 2;         // first graph of this block

    // ---- W fragments: read once per block, held in registers ----
    bf16x8 bfr[8][2];                        // [kk][nt] : 64 VGPR
    {
        const unsigned short* WTb = WT + (size_t)(colbase + c) * CIN + g * 8;
#pragma unroll
        for (int kk = 0; kk < 8; ++kk)
#pragma unroll
            for (int nt = 0; nt < 2; ++nt)
                bfr[kk][nt] = *reinterpret_cast<const bf16x8*>(WTb + nt * 16 * CIN + kk * 32);
    }
    float bias_c[2];
#pragma unroll
    for (int nt = 0; nt < 2; ++nt)
        bias_c[nt] = bias[colbase + nt * 16 + c];

    // ---- stage both graphs: X f32 -> LDS bf16 (swizzled), nt loads ----
    // 4096 chunks of 8 floats (2 graphs x 2048); 8 chunks/thread.
#pragma unroll
    for (int i = 0; i < 8; ++i) {
        int ch    = tid + i * 512;
        int graph = ch >> 11;
        int ch2   = ch & 2047;
        int row   = ch2 >> 5;
        int c8    = (ch2 & 31) << 3;
        const f32x4* p = reinterpret_cast<const f32x4*>(
            X + (size_t)(xg + graph) * (NNODE * CIN) + row * CIN + c8);
        f32x4 v0 = __builtin_nontemporal_load(p);
        f32x4 v1 = __builtin_nontemporal_load(p + 1);
        unsigned int w0 = f2bf_bits(v0[0]) | (f2bf_bits(v0[1]) << 16);
        unsigned int w1 = f2bf_bits(v0[2]) | (f2bf_bits(v0[3]) << 16);
        unsigned int w2 = f2bf_bits(v1[0]) | (f2bf_bits(v1[1]) << 16);
        unsigned int w3 = f2bf_bits(v1[2]) | (f2bf_bits(v1[3]) << 16);
        int byte = (row << 9) + (c8 << 1);
        byte ^= (row & 7) << 4;
        *reinterpret_cast<uint4*>((unsigned char*)Xs4[graph] + byte) =
            make_uint4(w0, w1, w2, w3);
    }
    __syncthreads();

    // ---- GEMM: both graphs interleaved, pure LDS + MFMA ----
    f32x4 acc[2][4][2] = {};                 // [graph][mt][nt]
    const int swz = (c & 7) << 4;
#pragma unroll
    for (int kk = 0; kk < 8; ++kk) {
        bf16x8 a[2][4];
#pragma unroll
        for (int gr = 0; gr < 2; ++gr)
#pragma unroll
            for (int mt = 0; mt < 4; ++mt) {
                int byte = ((mt * 16 + c) << 9) + (kk << 6) + (g << 4);
                byte ^= swz;
                a[gr][mt] = *reinterpret_cast<const bf16x8*>(
                    (const unsigned char*)Xs4[gr] + byte);
            }
#pragma unroll
        for (int gr = 0; gr < 2; ++gr)
#pragma unroll
            for (int mt = 0; mt < 4; ++mt)
#pragma unroll
                for (int nt = 0; nt < 2; ++nt)
                    acc[gr][mt][nt] = __builtin_amdgcn_mfma_f32_16x16x32_bf16(
                        a[gr][mt], bfr[kk][nt], acc[gr][mt][nt], 0, 0, 0);
    }

    // ---- epilogue: row-scale, prefix over 64 rows, bias+relu, nt stores ----
    float dd[4][4];                          // 1/sqrt(row+1) for this lane's rows
#pragma unroll
    for (int mt = 0; mt < 4; ++mt)
#pragma unroll
        for (int r = 0; r < 4; ++r)
            dd[mt][r] = rsqrtf((float)(mt * 16 + g * 4 + r + 1));

    float Ofs[2][4][2];                      // exclusive offsets [graph][mt][nt]
#pragma unroll
    for (int gr = 0; gr < 2; ++gr) {
        float t_[4][2];
#pragma unroll
        for (int mt = 0; mt < 4; ++mt)
#pragma unroll
            for (int nt = 0; nt < 2; ++nt) {
                f32x4 v = acc[gr][mt][nt];
                v[0] *= dd[mt][0]; v[1] *= dd[mt][1];
                v[2] *= dd[mt][2]; v[3] *= dd[mt][3];
                v[1] += v[0]; v[2] += v[1]; v[3] += v[2];
                acc[gr][mt][nt] = v;
                t_[mt][nt] = v[3];
            }
        // xor-butterfly exclusive scan over the 4 g-groups + serial over mt
#pragma unroll
        for (int nt = 0; nt < 2; ++nt) {
            float run = 0.0f;
#pragma unroll
            for (int mt = 0; mt < 4; ++mt) {
                float v    = t_[mt][nt];
                float p    = __shfl_xor(v, 16, 64);      // partner g^1
                float excl = (g & 1) ? p : 0.0f;
                float pair = v + p;
                float q    = __shfl_xor(pair, 32, 64);   // other pair's sum
                excl += (g & 2) ? q : 0.0f;
                Ofs[gr][mt][nt] = run + excl;
                run += pair + q;
            }
        }
    }

#pragma unroll
    for (int gr = 0; gr < 2; ++gr) {
        float* ob = out + (size_t)(xg + gr) * (NNODE * COUT) + colbase + c;
#pragma unroll
        for (int mt = 0; mt < 4; ++mt)
#pragma unroll
            for (int r = 0; r < 4; ++r) {
                const int row = mt * 16 + g * 4 + r;
                const float dr = dd[mt][r];
#pragma unroll
                for (int nt = 0; nt < 2; ++nt) {
                    float val = (acc[gr][mt][nt][r] + Ofs[gr][mt][nt]) * dr + bias_c[nt];
                    __builtin_nontemporal_store(fmaxf(val, 0.0f),
                                                ob + row * COUT + nt * 16);
                }
            }
    }
}

// W (f32, [K=256][N=256]) -> Wt (bf16 bits, [N=256][K=256])
__global__ void wprep(const float* __restrict__ W, unsigned short* __restrict__ Wt) {
    __shared__ unsigned short tile[64][72];
    const int tid = threadIdx.x;
    const int tk  = blockIdx.x & 3;
    const int tn  = blockIdx.x >> 2;
#pragma unroll
    for (int i = 0; i < 16; ++i) {
        int idx = tid + i * 256;
        int r  = idx >> 6;
        int cc = idx & 63;
        tile[cc][r] = (unsigned short)f2bf_bits(W[(tk * 64 + r) * 256 + tn * 64 + cc]);
    }
    __syncthreads();
#pragma unroll
    for (int i = 0; i < 16; ++i) {
        int idx = tid + i * 256;
        int rr = idx >> 6;
        int cc = idx & 63;
        Wt[(tn * 64 + rr) * 256 + tk * 64 + cc] = tile[rr][cc];
    }
}

extern "C" void kernel_launch(void* const* d_in, const int* in_sizes, int n_in,
                              void* d_out, int out_size, void* d_ws, size_t ws_size,
                              hipStream_t stream) {
    const float* x = (const float*)d_in[0];
    const float* W = (const float*)d_in[1];
    const float* bsp = (const float*)d_in[2];
    float* out = (float*)d_out;
    unsigned short* Wt = (unsigned short*)d_ws;

    hipLaunchKernelGGL(wprep, dim3(16), dim3(256), 0, stream, W, Wt);
    hipLaunchKernelGGL(gcn_fused, dim3(BATCH / 2), dim3(512), 0, stream, x, Wt, bsp, out);
}

// Round 5
// 25.751 us; speedup vs baseline: 1.5888x; 1.0690x over previous
//
#include <hip/hip_runtime.h>

// GCNConv, full upper-tri graph + self loops, B=512, N=64, C=O=256.
// out[b,i,:] = relu( (1/sqrt(i+1)) * sum_{j<=i} (X[b]W)[j,:]/sqrt(j+1) + bias )
//
// R6: R5 structure, register budget fixed. launch_bounds(512,1) -> <=256 VGPR
// (8 waves/CU), no spill. 2 graphs/block, load-all-then-convert staging,
// g1 loads issued before g0 compute so they fly under g0's MFMA+stores.
// W frags in regs (W read once per block: 32MB aggregate, L2-resident).

#define BATCH 512
#define NNODE 64
#define CIN   256
#define COUT  256

typedef __bf16 bf16x8 __attribute__((ext_vector_type(8)));
typedef float  f32x4  __attribute__((ext_vector_type(4)));

__device__ __forceinline__ unsigned int f2bf_bits(float f) {
    unsigned int u = __builtin_bit_cast(unsigned int, f);
    return (u + 0x7fffu + ((u >> 16) & 1u)) >> 16;
}

__global__ __launch_bounds__(512, 1) void gcn_fused(
    const float* __restrict__ X,
    const unsigned short* __restrict__ WT,   // bf16 bits, [COUT][CIN]
    const float* __restrict__ bias,
    float* __restrict__ out)
{
    __shared__ uint4 Xs4[2][2048];           // [graph][32KB] swizzled bf16 X
    const int tid  = threadIdx.x;
    const int lane = tid & 63;
    const int w    = tid >> 6;               // wave 0..7: cols [w*32, w*32+32)
    const int g    = lane >> 4;
    const int c    = lane & 15;
    const int colbase = w * 32;
    const int xg   = blockIdx.x * 2;

    const float* xb0 = X + (size_t)xg * (NNODE * CIN);
    const float* xb1 = xb0 + NNODE * CIN;

    // ---- issue g0 X loads (8 x float4 per thread = whole graph) ----
    f32x4 pf[8];
#pragma unroll
    for (int i = 0; i < 4; ++i) {
        int ch  = tid + i * 512;             // 2048 chunks of 8 floats
        const f32x4* p = reinterpret_cast<const f32x4*>(
            xb0 + (ch >> 5) * CIN + ((ch & 31) << 3));
        pf[2 * i]     = __builtin_nontemporal_load(p);
        pf[2 * i + 1] = __builtin_nontemporal_load(p + 1);
    }

    // ---- W fragments: read once per block (L2-resident), keep in regs ----
    bf16x8 bfr[8][2];                        // 64 VGPR
    {
        const unsigned short* WTb = WT + (size_t)(colbase + c) * CIN + g * 8;
#pragma unroll
        for (int kk = 0; kk < 8; ++kk)
#pragma unroll
            for (int nt = 0; nt < 2; ++nt)
                bfr[kk][nt] = *reinterpret_cast<const bf16x8*>(WTb + nt * 16 * CIN + kk * 32);
    }
    float bias_c[2];
#pragma unroll
    for (int nt = 0; nt < 2; ++nt)
        bias_c[nt] = bias[colbase + nt * 16 + c];

    // ---- convert g0 -> LDS buf0 (swizzled bf16) ----
#pragma unroll
    for (int i = 0; i < 4; ++i) {
        int ch  = tid + i * 512;
        int row = ch >> 5;
        int c8  = (ch & 31) << 3;
        f32x4 v0 = pf[2 * i], v1 = pf[2 * i + 1];
        unsigned int w0 = f2bf_bits(v0[0]) | (f2bf_bits(v0[1]) << 16);
        unsigned int w1 = f2bf_bits(v0[2]) | (f2bf_bits(v0[3]) << 16);
        unsigned int w2 = f2bf_bits(v1[0]) | (f2bf_bits(v1[1]) << 16);
        unsigned int w3 = f2bf_bits(v1[2]) | (f2bf_bits(v1[3]) << 16);
        int byte = (row << 9) + (c8 << 1);
        byte ^= (row & 7) << 4;
        *reinterpret_cast<uint4*>((unsigned char*)Xs4[0] + byte) =
            make_uint4(w0, w1, w2, w3);
    }
    // ---- issue g1 X loads (fly under g0 compute + stores) ----
    f32x4 pg[8];
#pragma unroll
    for (int i = 0; i < 4; ++i) {
        int ch  = tid + i * 512;
        const f32x4* p = reinterpret_cast<const f32x4*>(
            xb1 + (ch >> 5) * CIN + ((ch & 31) << 3));
        pg[2 * i]     = __builtin_nontemporal_load(p);
        pg[2 * i + 1] = __builtin_nontemporal_load(p + 1);
    }

    float dd[4][4];                          // 1/sqrt(row+1) table
#pragma unroll
    for (int mt = 0; mt < 4; ++mt)
#pragma unroll
        for (int r = 0; r < 4; ++r)
            dd[mt][r] = rsqrtf((float)(mt * 16 + g * 4 + r + 1));

    const int swz = (c & 7) << 4;

    // ---- per-graph compute: GEMM + scaled prefix scan + bias/relu/store ----
    auto compute_graph = [&](const unsigned char* Xs, float* ob) {
        f32x4 acc[4][2] = {};                // [mt][nt]
#pragma unroll
        for (int kk = 0; kk < 8; ++kk) {
            bf16x8 a[4];
#pragma unroll
            for (int mt = 0; mt < 4; ++mt) {
                int byte = ((mt * 16 + c) << 9) + (kk << 6) + (g << 4);
                byte ^= swz;
                a[mt] = *reinterpret_cast<const bf16x8*>(Xs + byte);
            }
#pragma unroll
            for (int mt = 0; mt < 4; ++mt)
#pragma unroll
                for (int nt = 0; nt < 2; ++nt)
                    acc[mt][nt] = __builtin_amdgcn_mfma_f32_16x16x32_bf16(
                        a[mt], bfr[kk][nt], acc[mt][nt], 0, 0, 0);
        }
        // per-lane inclusive scan within each 4-row chunk
        float t_[4][2];
#pragma unroll
        for (int mt = 0; mt < 4; ++mt)
#pragma unroll
            for (int nt = 0; nt < 2; ++nt) {
                f32x4 v = acc[mt][nt];
                v[0] *= dd[mt][0]; v[1] *= dd[mt][1];
                v[2] *= dd[mt][2]; v[3] *= dd[mt][3];
                v[1] += v[0]; v[2] += v[1]; v[3] += v[2];
                acc[mt][nt] = v;
                t_[mt][nt] = v[3];
            }
        // xor-butterfly exclusive scan over 4 g-groups, serial over mt
        float Ofs[4][2];
#pragma unroll
        for (int nt = 0; nt < 2; ++nt) {
            float run = 0.0f;
#pragma unroll
            for (int mt = 0; mt < 4; ++mt) {
                float v    = t_[mt][nt];
                float p    = __shfl_xor(v, 16, 64);
                float excl = (g & 1) ? p : 0.0f;
                float pair = v + p;
                float q    = __shfl_xor(pair, 32, 64);
                excl += (g & 2) ? q : 0.0f;
                Ofs[mt][nt] = run + excl;
                run += pair + q;
            }
        }
#pragma unroll
        for (int mt = 0; mt < 4; ++mt)
#pragma unroll
            for (int r = 0; r < 4; ++r) {
                const int row = mt * 16 + g * 4 + r;
                const float dr = dd[mt][r];
#pragma unroll
                for (int nt = 0; nt < 2; ++nt) {
                    float val = (acc[mt][nt][r] + Ofs[mt][nt]) * dr + bias_c[nt];
                    __builtin_nontemporal_store(fmaxf(val, 0.0f),
                                                ob + row * COUT + nt * 16);
                }
            }
    };

    __syncthreads();
    compute_graph((const unsigned char*)Xs4[0],
                  out + (size_t)xg * (NNODE * COUT) + colbase + c);

    // ---- convert g1 -> LDS buf1 (loads have been in flight) ----
#pragma unroll
    for (int i = 0; i < 4; ++i) {
        int ch  = tid + i * 512;
        int row = ch >> 5;
        int c8  = (ch & 31) << 3;
        f32x4 v0 = pg[2 * i], v1 = pg[2 * i + 1];
        unsigned int w0 = f2bf_bits(v0[0]) | (f2bf_bits(v0[1]) << 16);
        unsigned int w1 = f2bf_bits(v0[2]) | (f2bf_bits(v0[3]) << 16);
        unsigned int w2 = f2bf_bits(v1[0]) | (f2bf_bits(v1[1]) << 16);
        unsigned int w3 = f2bf_bits(v1[2]) | (f2bf_bits(v1[3]) << 16);
        int byte = (row << 9) + (c8 << 1);
        byte ^= (row & 7) << 4;
        *reinterpret_cast<uint4*>((unsigned char*)Xs4[1] + byte) =
            make_uint4(w0, w1, w2, w3);
    }
    __syncthreads();
    compute_graph((const unsigned char*)Xs4[1],
                  out + (size_t)(xg + 1) * (NNODE * COUT) + colbase + c);
}

// W (f32, [K=256][N=256]) -> Wt (bf16 bits, [N=256][K=256])
__global__ void wprep(const float* __restrict__ W, unsigned short* __restrict__ Wt) {
    __shared__ unsigned short tile[64][72];
    const int tid = threadIdx.x;
    const int tk  = blockIdx.x & 3;
    const int tn  = blockIdx.x >> 2;
#pragma unroll
    for (int i = 0; i < 16; ++i) {
        int idx = tid + i * 256;
        int r  = idx >> 6;
        int cc = idx & 63;
        tile[cc][r] = (unsigned short)f2bf_bits(W[(tk * 64 + r) * 256 + tn * 64 + cc]);
    }
    __syncthreads();
#pragma unroll
    for (int i = 0; i < 16; ++i) {
        int idx = tid + i * 256;
        int rr = idx >> 6;
        int cc = idx & 63;
        Wt[(tn * 64 + rr) * 256 + tk * 64 + cc] = tile[rr][cc];
    }
}

extern "C" void kernel_launch(void* const* d_in, const int* in_sizes, int n_in,
                              void* d_out, int out_size, void* d_ws, size_t ws_size,
                              hipStream_t stream) {
    const float* x = (const float*)d_in[0];
    const float* W = (const float*)d_in[1];
    const float* bsp = (const float*)d_in[2];
    float* out = (float*)d_out;
    unsigned short* Wt = (unsigned short*)d_ws;

    hipLaunchKernelGGL(wprep, dim3(16), dim3(256), 0, stream, W, Wt);
    hipLaunchKernelGGL(gcn_fused, dim3(BATCH / 2), dim3(512), 0, stream, x, Wt, bsp, out);
}

// Round 6
// 25.313 us; speedup vs baseline: 1.6162x; 1.0173x over previous
//
#include <hip/hip_runtime.h>

// GCNConv, full upper-tri graph + self loops, B=512, N=64, C=O=256.
// out[b,i,:] = relu( (1/sqrt(i+1)) * sum_{j<=i} (X[b]W)[j,:]/sqrt(j+1) + bias )
//
// R7: SINGLE kernel (wprep eliminated). W panel loaded per-block directly from
// f32 W via strided L2-resident loads into registers (one-time, overlapped
// with X HBM loads). Otherwise identical to R6: 2 graphs/block, grid 256,
// 512 thr, launch_bounds(512,1), reg-staged X -> swizzled bf16 LDS, g1 loads
// in flight under g0 compute. Stores are plain (no NT) for L2 write-combine.

#define BATCH 512
#define NNODE 64
#define CIN   256
#define COUT  256

typedef __bf16 bf16x8 __attribute__((ext_vector_type(8)));
typedef float  f32x4  __attribute__((ext_vector_type(4)));

__device__ __forceinline__ unsigned int f2bf_bits(float f) {
    unsigned int u = __builtin_bit_cast(unsigned int, f);
    return (u + 0x7fffu + ((u >> 16) & 1u)) >> 16;
}

__device__ __forceinline__ __bf16 f2bf(float f) {
    unsigned short us = (unsigned short)f2bf_bits(f);
    return __builtin_bit_cast(__bf16, us);
}

__global__ __launch_bounds__(512, 1) void gcn_fused(
    const float* __restrict__ X,
    const float* __restrict__ W,             // f32, [CIN][COUT] row-major
    const float* __restrict__ bias,
    float* __restrict__ out)
{
    __shared__ uint4 Xs4[2][2048];           // [graph][32KB] swizzled bf16 X
    const int tid  = threadIdx.x;
    const int lane = tid & 63;
    const int w    = tid >> 6;               // wave 0..7: cols [w*32, w*32+32)
    const int g    = lane >> 4;
    const int c    = lane & 15;
    const int colbase = w * 32;
    const int xg   = blockIdx.x * 2;

    const float* xb0 = X + (size_t)xg * (NNODE * CIN);
    const float* xb1 = xb0 + NNODE * CIN;

    // ---- issue g0 X loads (8 x float4 per thread = whole graph) ----
    f32x4 pf[8];
#pragma unroll
    for (int i = 0; i < 4; ++i) {
        int ch  = tid + i * 512;             // 2048 chunks of 8 floats
        const f32x4* p = reinterpret_cast<const f32x4*>(
            xb0 + (ch >> 5) * CIN + ((ch & 31) << 3));
        pf[2 * i]     = __builtin_nontemporal_load(p);
        pf[2 * i + 1] = __builtin_nontemporal_load(p + 1);
    }

    // ---- W fragments direct from f32 W (L2-resident), one-time, in regs ----
    // B[k = kk*32+g*8+j][col = colbase+nt*16+c] = W[k*COUT + col]
    bf16x8 bfr[8][2];                        // 64 VGPR
    {
        const float* Wp = W + colbase + c;
#pragma unroll
        for (int kk = 0; kk < 8; ++kk)
#pragma unroll
            for (int nt = 0; nt < 2; ++nt) {
                bf16x8 t;
#pragma unroll
                for (int j = 0; j < 8; ++j)
                    t[j] = f2bf(Wp[(size_t)(kk * 32 + g * 8 + j) * COUT + nt * 16]);
                bfr[kk][nt] = t;
            }
    }
    float bias_c[2];
#pragma unroll
    for (int nt = 0; nt < 2; ++nt)
        bias_c[nt] = bias[colbase + nt * 16 + c];

    // ---- convert g0 -> LDS buf0 (swizzled bf16) ----
#pragma unroll
    for (int i = 0; i < 4; ++i) {
        int ch  = tid + i * 512;
        int row = ch >> 5;
        int c8  = (ch & 31) << 3;
        f32x4 v0 = pf[2 * i], v1 = pf[2 * i + 1];
        unsigned int w0 = f2bf_bits(v0[0]) | (f2bf_bits(v0[1]) << 16);
        unsigned int w1 = f2bf_bits(v0[2]) | (f2bf_bits(v0[3]) << 16);
        unsigned int w2 = f2bf_bits(v1[0]) | (f2bf_bits(v1[1]) << 16);
        unsigned int w3 = f2bf_bits(v1[2]) | (f2bf_bits(v1[3]) << 16);
        int byte = (row << 9) + (c8 << 1);
        byte ^= (row & 7) << 4;
        *reinterpret_cast<uint4*>((unsigned char*)Xs4[0] + byte) =
            make_uint4(w0, w1, w2, w3);
    }
    // ---- issue g1 X loads (fly under g0 compute + stores) ----
    f32x4 pg[8];
#pragma unroll
    for (int i = 0; i < 4; ++i) {
        int ch  = tid + i * 512;
        const f32x4* p = reinterpret_cast<const f32x4*>(
            xb1 + (ch >> 5) * CIN + ((ch & 31) << 3));
        pg[2 * i]     = __builtin_nontemporal_load(p);
        pg[2 * i + 1] = __builtin_nontemporal_load(p + 1);
    }

    float dd[4][4];                          // 1/sqrt(row+1) table
#pragma unroll
    for (int mt = 0; mt < 4; ++mt)
#pragma unroll
        for (int r = 0; r < 4; ++r)
            dd[mt][r] = rsqrtf((float)(mt * 16 + g * 4 + r + 1));

    const int swz = (c & 7) << 4;

    // ---- per-graph compute: GEMM + scaled prefix scan + bias/relu/store ----
    auto compute_graph = [&](const unsigned char* Xs, float* ob) {
        f32x4 acc[4][2] = {};                // [mt][nt]
#pragma unroll
        for (int kk = 0; kk < 8; ++kk) {
            bf16x8 a[4];
#pragma unroll
            for (int mt = 0; mt < 4; ++mt) {
                int byte = ((mt * 16 + c) << 9) + (kk << 6) + (g << 4);
                byte ^= swz;
                a[mt] = *reinterpret_cast<const bf16x8*>(Xs + byte);
            }
#pragma unroll
            for (int mt = 0; mt < 4; ++mt)
#pragma unroll
                for (int nt = 0; nt < 2; ++nt)
                    acc[mt][nt] = __builtin_amdgcn_mfma_f32_16x16x32_bf16(
                        a[mt], bfr[kk][nt], acc[mt][nt], 0, 0, 0);
        }
        // per-lane inclusive scan within each 4-row chunk
        float t_[4][2];
#pragma unroll
        for (int mt = 0; mt < 4; ++mt)
#pragma unroll
            for (int nt = 0; nt < 2; ++nt) {
                f32x4 v = acc[mt][nt];
                v[0] *= dd[mt][0]; v[1] *= dd[mt][1];
                v[2] *= dd[mt][2]; v[3] *= dd[mt][3];
                v[1] += v[0]; v[2] += v[1]; v[3] += v[2];
                acc[mt][nt] = v;
                t_[mt][nt] = v[3];
            }
        // xor-butterfly exclusive scan over 4 g-groups, serial over mt
        float Ofs[4][2];
#pragma unroll
        for (int nt = 0; nt < 2; ++nt) {
            float run = 0.0f;
#pragma unroll
            for (int mt = 0; mt < 4; ++mt) {
                float v    = t_[mt][nt];
                float p    = __shfl_xor(v, 16, 64);
                float excl = (g & 1) ? p : 0.0f;
                float pair = v + p;
                float q    = __shfl_xor(pair, 32, 64);
                excl += (g & 2) ? q : 0.0f;
                Ofs[mt][nt] = run + excl;
                run += pair + q;
            }
        }
#pragma unroll
        for (int mt = 0; mt < 4; ++mt)
#pragma unroll
            for (int r = 0; r < 4; ++r) {
                const int row = mt * 16 + g * 4 + r;
                const float dr = dd[mt][r];
#pragma unroll
                for (int nt = 0; nt < 2; ++nt) {
                    float val = (acc[mt][nt][r] + Ofs[mt][nt]) * dr + bias_c[nt];
                    ob[row * COUT + nt * 16] = fmaxf(val, 0.0f);
                }
            }
    };

    __syncthreads();
    compute_graph((const unsigned char*)Xs4[0],
                  out + (size_t)xg * (NNODE * COUT) + colbase + c);

    // ---- convert g1 -> LDS buf1 (loads have been in flight) ----
#pragma unroll
    for (int i = 0; i < 4; ++i) {
        int ch  = tid + i * 512;
        int row = ch >> 5;
        int c8  = (ch & 31) << 3;
        f32x4 v0 = pg[2 * i], v1 = pg[2 * i + 1];
        unsigned int w0 = f2bf_bits(v0[0]) | (f2bf_bits(v0[1]) << 16);
        unsigned int w1 = f2bf_bits(v0[2]) | (f2bf_bits(v0[3]) << 16);
        unsigned int w2 = f2bf_bits(v1[0]) | (f2bf_bits(v1[1]) << 16);
        unsigned int w3 = f2bf_bits(v1[2]) | (f2bf_bits(v1[3]) << 16);
        int byte = (row << 9) + (c8 << 1);
        byte ^= (row & 7) << 4;
        *reinterpret_cast<uint4*>((unsigned char*)Xs4[1] + byte) =
            make_uint4(w0, w1, w2, w3);
    }
    __syncthreads();
    compute_graph((const unsigned char*)Xs4[1],
                  out + (size_t)(xg + 1) * (NNODE * COUT) + colbase + c);
}

extern "C" void kernel_launch(void* const* d_in, const int* in_sizes, int n_in,
                              void* d_out, int out_size, void* d_ws, size_t ws_size,
                              hipStream_t stream) {
    const float* x = (const float*)d_in[0];
    const float* W = (const float*)d_in[1];
    const float* bsp = (const float*)d_in[2];
    float* out = (float*)d_out;

    hipLaunchKernelGGL(gcn_fused, dim3(BATCH / 2), dim3(512), 0, stream,
                       x, W, bsp, out);
}

// Round 7
// 20.189 us; speedup vs baseline: 2.0265x; 1.2538x over previous
//
#include <hip/hip_runtime.h>

// GCNConv, full upper-tri graph + self loops, B=512, N=64, C=O=256.
// out[b,i,:] = relu( (1/sqrt(i+1)) * sum_{j<=i} (X[b]W)[j,:]/sqrt(j+1) + bias )
//
// R8: fix the barrier-drain serialization. __syncthreads == s_waitcnt vmcnt(0)
// + s_barrier, so issuing g1's loads BEFORE the barrier (R5-R7) made the whole
// block wait for them before computing g0. Now: barrier FIRST (trivial drain),
// THEN issue g1 loads, then compute g0 -- g1 streams in under g0's MFMA+stores
// and the g1-convert wait is a wave-local counted vmcnt, not a block drain.
// Also: native (__bf16) casts (packed cvt_pk) instead of manual integer RNE.

#define BATCH 512
#define NNODE 64
#define CIN   256
#define COUT  256

typedef __bf16 bf16x8 __attribute__((ext_vector_type(8)));
typedef float  f32x4  __attribute__((ext_vector_type(4)));

__global__ __launch_bounds__(512, 1) void gcn_fused(
    const float* __restrict__ X,
    const float* __restrict__ W,             // f32, [CIN][COUT] row-major
    const float* __restrict__ bias,
    float* __restrict__ out)
{
    __shared__ uint4 Xs4[2][2048];           // [graph][32KB] swizzled bf16 X
    const int tid  = threadIdx.x;
    const int lane = tid & 63;
    const int w    = tid >> 6;               // wave 0..7: cols [w*32, w*32+32)
    const int g    = lane >> 4;
    const int c    = lane & 15;
    const int colbase = w * 32;
    const int xg   = blockIdx.x * 2;

    const float* xb0 = X + (size_t)xg * (NNODE * CIN);
    const float* xb1 = xb0 + NNODE * CIN;

    // ---- issue g0 X loads (4 chunks of 8 floats per thread) ----
    f32x4 pf[8];
#pragma unroll
    for (int i = 0; i < 4; ++i) {
        int ch  = tid + i * 512;             // 2048 chunks of 8 floats
        const f32x4* p = reinterpret_cast<const f32x4*>(
            xb0 + (ch >> 5) * CIN + ((ch & 31) << 3));
        pf[2 * i]     = p[0];
        pf[2 * i + 1] = p[1];
    }

    // ---- W fragments direct from f32 W (L2-resident), one-time, in regs ----
    // B[k = kk*32+g*8+j][col = colbase+nt*16+c] = W[k*COUT + col]
    bf16x8 bfr[8][2];                        // 64 VGPR
    {
        const float* Wp = W + colbase + c;
#pragma unroll
        for (int kk = 0; kk < 8; ++kk)
#pragma unroll
            for (int nt = 0; nt < 2; ++nt) {
                bf16x8 t;
#pragma unroll
                for (int j = 0; j < 8; ++j)
                    t[j] = (__bf16)Wp[(size_t)(kk * 32 + g * 8 + j) * COUT + nt * 16];
                bfr[kk][nt] = t;
            }
    }
    float bias_c[2];
#pragma unroll
    for (int nt = 0; nt < 2; ++nt)
        bias_c[nt] = bias[colbase + nt * 16 + c];

    // ---- convert g0 -> LDS buf0 (swizzled bf16) ----
#pragma unroll
    for (int i = 0; i < 4; ++i) {
        int ch  = tid + i * 512;
        int row = ch >> 5;
        int c8  = (ch & 31) << 3;
        f32x4 v0 = pf[2 * i], v1 = pf[2 * i + 1];
        bf16x8 h;
        h[0] = (__bf16)v0[0]; h[1] = (__bf16)v0[1];
        h[2] = (__bf16)v0[2]; h[3] = (__bf16)v0[3];
        h[4] = (__bf16)v1[0]; h[5] = (__bf16)v1[1];
        h[6] = (__bf16)v1[2]; h[7] = (__bf16)v1[3];
        int byte = (row << 9) + (c8 << 1);
        byte ^= (row & 7) << 4;
        *reinterpret_cast<uint4*>((unsigned char*)Xs4[0] + byte) =
            __builtin_bit_cast(uint4, h);
    }

    float dd[4][4];                          // 1/sqrt(row+1) table
#pragma unroll
    for (int mt = 0; mt < 4; ++mt)
#pragma unroll
        for (int r = 0; r < 4; ++r)
            dd[mt][r] = rsqrtf((float)(mt * 16 + g * 4 + r + 1));

    const int swz = (c & 7) << 4;

    // ---- per-graph compute: GEMM + scaled prefix scan + bias/relu/store ----
    auto compute_graph = [&](const unsigned char* Xs, float* ob) {
        f32x4 acc[4][2] = {};                // [mt][nt]
#pragma unroll
        for (int kk = 0; kk < 8; ++kk) {
            bf16x8 a[4];
#pragma unroll
            for (int mt = 0; mt < 4; ++mt) {
                int byte = ((mt * 16 + c) << 9) + (kk << 6) + (g << 4);
                byte ^= swz;
                a[mt] = *reinterpret_cast<const bf16x8*>(Xs + byte);
            }
#pragma unroll
            for (int mt = 0; mt < 4; ++mt)
#pragma unroll
                for (int nt = 0; nt < 2; ++nt)
                    acc[mt][nt] = __builtin_amdgcn_mfma_f32_16x16x32_bf16(
                        a[mt], bfr[kk][nt], acc[mt][nt], 0, 0, 0);
        }
        // per-lane inclusive scan within each 4-row chunk
        float t_[4][2];
#pragma unroll
        for (int mt = 0; mt < 4; ++mt)
#pragma unroll
            for (int nt = 0; nt < 2; ++nt) {
                f32x4 v = acc[mt][nt];
                v[0] *= dd[mt][0]; v[1] *= dd[mt][1];
                v[2] *= dd[mt][2]; v[3] *= dd[mt][3];
                v[1] += v[0]; v[2] += v[1]; v[3] += v[2];
                acc[mt][nt] = v;
                t_[mt][nt] = v[3];
            }
        // xor-butterfly exclusive scan over 4 g-groups, serial over mt
        float Ofs[4][2];
#pragma unroll
        for (int nt = 0; nt < 2; ++nt) {
            float run = 0.0f;
#pragma unroll
            for (int mt = 0; mt < 4; ++mt) {
                float v    = t_[mt][nt];
                float p    = __shfl_xor(v, 16, 64);
                float excl = (g & 1) ? p : 0.0f;
                float pair = v + p;
                float q    = __shfl_xor(pair, 32, 64);
                excl += (g & 2) ? q : 0.0f;
                Ofs[mt][nt] = run + excl;
                run += pair + q;
            }
        }
#pragma unroll
        for (int mt = 0; mt < 4; ++mt)
#pragma unroll
            for (int r = 0; r < 4; ++r) {
                const int row = mt * 16 + g * 4 + r;
                const float dr = dd[mt][r];
#pragma unroll
                for (int nt = 0; nt < 2; ++nt) {
                    float val = (acc[mt][nt][r] + Ofs[mt][nt]) * dr + bias_c[nt];
                    ob[row * COUT + nt * 16] = fmaxf(val, 0.0f);
                }
            }
    };

    // barrier BEFORE issuing g1 loads: nothing outstanding -> trivial drain
    __syncthreads();

    // ---- issue g1 X loads: they fly under g0's compute + stores ----
    f32x4 pg[8];
#pragma unroll
    for (int i = 0; i < 4; ++i) {
        int ch  = tid + i * 512;
        const f32x4* p = reinterpret_cast<const f32x4*>(
            xb1 + (ch >> 5) * CIN + ((ch & 31) << 3));
        pg[2 * i]     = p[0];
        pg[2 * i + 1] = p[1];
    }

    compute_graph((const unsigned char*)Xs4[0],
                  out + (size_t)xg * (NNODE * COUT) + colbase + c);

    // ---- convert g1 -> LDS buf1 (wave-local vmcnt wait, not a block drain) ----
#pragma unroll
    for (int i = 0; i < 4; ++i) {
        int ch  = tid + i * 512;
        int row = ch >> 5;
        int c8  = (ch & 31) << 3;
        f32x4 v0 = pg[2 * i], v1 = pg[2 * i + 1];
        bf16x8 h;
        h[0] = (__bf16)v0[0]; h[1] = (__bf16)v0[1];
        h[2] = (__bf16)v0[2]; h[3] = (__bf16)v0[3];
        h[4] = (__bf16)v1[0]; h[5] = (__bf16)v1[1];
        h[6] = (__bf16)v1[2]; h[7] = (__bf16)v1[3];
        int byte = (row << 9) + (c8 << 1);
        byte ^= (row & 7) << 4;
        *reinterpret_cast<uint4*>((unsigned char*)Xs4[1] + byte) =
            __builtin_bit_cast(uint4, h);
    }
    __syncthreads();
    compute_graph((const unsigned char*)Xs4[1],
                  out + (size_t)(xg + 1) * (NNODE * COUT) + colbase + c);
}

extern "C" void kernel_launch(void* const* d_in, const int* in_sizes, int n_in,
                              void* d_out, int out_size, void* d_ws, size_t ws_size,
                              hipStream_t stream) {
    const float* x = (const float*)d_in[0];
    const float* W = (const float*)d_in[1];
    const float* bsp = (const float*)d_in[2];
    float* out = (float*)d_out;

    hipLaunchKernelGGL(gcn_fused, dim3(BATCH / 2), dim3(512), 0, stream,
                       x, W, bsp, out);
}